// Round 10
// baseline (218.291 us; speedup 1.0000x reference)
//
#include <hip/hip_runtime.h>
#include <hip/hip_bf16.h>
#include <math.h>

#define N_ATOMS 4096
#define L_WORDS 65536
#define DD 10
#define HALO 11

#define CONV_BLOCKS 256
#define CONV_BLOCK 256
#define GNN_BLOCKS 512            // 128 row-groups x 4 column quarters
#define RPW 8                     // rows per wave
#define RPB 32                    // rows per block (4 waves)
#define QCOLS 1024                // columns per quarter

typedef float v4f __attribute__((ext_vector_type(4)));

// part layout: [n][q][d]  (n*40 + q*10 + d) — staging reads 160 B contiguous.

// ---------------------------------------------------------------------------
// K1: fused_layer — role-split grid, NO atomics / NO fences.
//  blocks [0,256):   CNN layer (VALU-bound, hidden under GNN memory waits)
//  blocks [256,768): GNN partial A@hs over a 1024-column quarter.
// XCD note: XCD = blockIdx%8 and q = (blockIdx-256)%4 => each XCD handles a
// single quarter; its 360-KB staging set (embed rows + p0 + p1 slices) stays
// in the 4-MB L2 — A uses non-temporal loads so it can't evict it.
// Embedding is gathered directly in staging (no xs0 buffer, no embed kernel).
// ---------------------------------------------------------------------------
__global__ __launch_bounds__(256, 3) void fused_layer(
    const float* __restrict__ A,
    const int* __restrict__ fp,
    const float* __restrict__ embed_fp,
    const float* __restrict__ p0,        // prev part (null in L0)
    const float* __restrict__ p1,        // prev-prev part (null in L0/L1)
    float* __restrict__ part,            // this layer's output [4096][4][10]
    const float* __restrict__ Wg, const float* __restrict__ bg,
    const float* __restrict__ tin, const int* __restrict__ words,
    const float* __restrict__ embed_word, const float* __restrict__ w,
    const float* __restrict__ bptr, float* __restrict__ tout)
{
    __shared__ float sh[DD * QCOLS];     // 40 KB exactly
    const int tid = threadIdx.x;

    if (blockIdx.x < CONV_BLOCKS) {
        // ================= CONV ROLE =================
        float* s = sh;                   // (256+22)*11 floats, stride 11
        const int l0 = blockIdx.x * CONV_BLOCK;
        for (int idx = tid; idx < (CONV_BLOCK + 2 * HALO) * DD; idx += CONV_BLOCK) {
            int rr = idx / DD, d = idx - rr * DD;
            int gr = l0 - HALO + rr;
            float v = 0.f;
            if (gr >= 0 && gr < L_WORDS) {
                if (tin) v = tin[(size_t)gr * DD + d];
                else     v = embed_word[(size_t)words[gr] * DD + d];
            }
            s[rr * 11 + d] = v;
        }
        __syncthreads();

        const float bias = *bptr;
        float acc[DD];
        #pragma unroll
        for (int d = 0; d < DD; ++d) acc[d] = bias;
        for (int i = 0; i < 23; ++i) {
            float row[DD];
            const float* sr = &s[(tid + i) * 11];
            #pragma unroll
            for (int c = 0; c < DD; ++c) row[c] = sr[c];
            #pragma unroll
            for (int d = 0; d < DD; ++d) {
                #pragma unroll
                for (int c = 0; c < DD; ++c)
                    acc[d] += row[c] * w[i * 23 + (c - d + 11)];
            }
        }
        const int l = l0 + tid;
        #pragma unroll
        for (int d = 0; d < DD; ++d)
            tout[(size_t)l * DD + d] = fmaxf(acc[d], 0.f);
    } else {
        // ================= GNN ROLE =================
        const int b = blockIdx.x - CONV_BLOCKS;     // 0..511
        const int wave = tid >> 6, lane = tid & 63;
        const int q = b & 3, rg = b >> 2;           // quarter / row group
        const int qbase = q * QCOLS;

        // ---- stage hs for this quarter: gather embed + contiguous part reads
        for (int j = 0; j < 4; ++j) {
            const int lc = j * 256 + tid;           // local col, lanes dense
            const int n = qbase + lc;
            float x[DD];
            const float* e = embed_fp + (size_t)fp[n] * DD;
            #pragma unroll
            for (int d = 0; d < DD; ++d) x[d] = e[d];
            if (p0) {
                const float* pp = p0 + (size_t)n * 40;   // 160 B contiguous
                #pragma unroll
                for (int qq = 0; qq < 4; ++qq)
                    #pragma unroll
                    for (int d = 0; d < DD; ++d) x[d] += pp[qq * 10 + d];
            }
            if (p1) {
                const float* pp = p1 + (size_t)n * 40;
                #pragma unroll
                for (int qq = 0; qq < 4; ++qq)
                    #pragma unroll
                    for (int d = 0; d < DD; ++d) x[d] += pp[qq * 10 + d];
            }
            #pragma unroll
            for (int d = 0; d < DD; ++d) {
                float v = bg[d];
                #pragma unroll
                for (int k = 0; k < DD; ++k) v += Wg[d * DD + k] * x[k];
                sh[d * QCOLS + lc] = fmaxf(v, 0.f);   // lanes dense: no conflict
            }
        }
        __syncthreads();

        const int r0 = rg * RPB + wave * RPW;
        const v4f* A4 = (const v4f*)(A + (size_t)r0 * N_ATOMS) + q * (QCOLS / 4);
        const v4f* sh4 = (const v4f*)sh;

        float acc[RPW][DD];
        #pragma unroll
        for (int r = 0; r < RPW; ++r)
            #pragma unroll
            for (int d = 0; d < DD; ++d) acc[r][d] = 0.f;

        // h kept in VGPRs; A consumed in two 4-row batches so the compiler
        // emits decreasing vmcnt waits instead of a wait-all. nt loads keep
        // the streaming A out of the staging-shared L2.
        #pragma unroll 1
        for (int it = 0; it < 4; ++it) {
            const int cb = it * 64 + lane;
            v4f h4[DD];
            #pragma unroll
            for (int d = 0; d < DD; ++d) h4[d] = sh4[d * 256 + cb];
            #pragma unroll
            for (int rb = 0; rb < RPW; rb += 4) {
                v4f a[4];
                #pragma unroll
                for (int r = 0; r < 4; ++r)
                    a[r] = __builtin_nontemporal_load(
                        &A4[(size_t)(rb + r) * (N_ATOMS / 4) + cb]);
                #pragma unroll
                for (int r = 0; r < 4; ++r) {
                    #pragma unroll
                    for (int d = 0; d < DD; ++d) {
                        acc[rb + r][d] += a[r].x * h4[d].x;
                        acc[rb + r][d] += a[r].y * h4[d].y;
                        acc[rb + r][d] += a[r].z * h4[d].z;
                        acc[rb + r][d] += a[r].w * h4[d].w;
                    }
                }
            }
        }

        // ---- reduction: 3 xor steps within 8-lane groups + LDS finish ----
        #pragma unroll
        for (int m = 1; m <= 4; m <<= 1) {
            #pragma unroll
            for (int r = 0; r < RPW; ++r)
                #pragma unroll
                for (int d = 0; d < DD; ++d)
                    acc[r][d] += __shfl_xor(acc[r][d], m, 64);
        }
        __syncthreads();   // hs in LDS no longer needed

        if ((lane & 7) == 0) {
            const int g = lane >> 3;
            float* dst = &sh[(wave * 8 + g) * 80];
            #pragma unroll
            for (int r = 0; r < RPW; ++r)
                #pragma unroll
                for (int d = 0; d < DD; ++d) dst[r * DD + d] = acc[r][d];
        }
        __syncthreads();

        // block finish: 320 outputs (32 rows x 10) -> part[n][q][d]
        float* pbase = part + (size_t)rg * (RPB * 40) + q * 10;
        for (int o = tid; o < RPB * DD; o += 256) {
            const int w8 = o / 80;           // wave
            const int k = o - w8 * 80;       // r*10+d
            float v = 0.f;
            #pragma unroll
            for (int g = 0; g < 8; ++g) v += sh[(w8 * 8 + g) * 80 + k];
            const int row = w8 * 8 + k / 10;
            const int d = k % 10;
            pbase[row * 40 + d] = v;
        }
    }
}

// ---------------------------------------------------------------------------
// K2: comp_reduce — comp_part[16][10]; x = embed + sum of all part slices
// ---------------------------------------------------------------------------
__global__ __launch_bounds__(256) void comp_reduce(
    const int* __restrict__ fp, const float* __restrict__ embed_fp,
    const float* __restrict__ p0, const float* __restrict__ p1,
    const float* __restrict__ p2, float* __restrict__ comp_part)
{
    const int tid = threadIdx.x, wave = tid >> 6, lane = tid & 63;
    const int n = blockIdx.x * 256 + tid;
    float x[DD];
    const float* e = embed_fp + (size_t)fp[n] * DD;
    #pragma unroll
    for (int d = 0; d < DD; ++d) x[d] = e[d];
    const float* a0 = p0 + (size_t)n * 40;
    const float* a1 = p1 + (size_t)n * 40;
    const float* a2 = p2 + (size_t)n * 40;
    #pragma unroll
    for (int qq = 0; qq < 4; ++qq)
        #pragma unroll
        for (int d = 0; d < DD; ++d)
            x[d] += a0[qq * 10 + d] + a1[qq * 10 + d] + a2[qq * 10 + d];
    #pragma unroll
    for (int m = 32; m >= 1; m >>= 1) {
        #pragma unroll
        for (int d = 0; d < DD; ++d) x[d] += __shfl_xor(x[d], m, 64);
    }
    __shared__ float s[4][DD];
    if (lane == 0) {
        #pragma unroll
        for (int d = 0; d < DD; ++d) s[wave][d] = x[d];
    }
    __syncthreads();
    if (tid < DD)
        comp_part[blockIdx.x * DD + tid] =
            s[0][tid] + s[1][tid] + s[2][tid] + s[3][tid];
}

// ---------------------------------------------------------------------------
// K3: attention pooling (comp derived in-block from comp_part)
// ---------------------------------------------------------------------------
__global__ __launch_bounds__(1024) void attention_pool(
    const float* __restrict__ xs_p, const float* __restrict__ comp_part,
    const float* __restrict__ Wa, const float* __restrict__ ba,
    float* __restrict__ att_part)
{
    __shared__ float shc[DD];
    __shared__ float s[16][DD];
    const int tid = threadIdx.x, wave = tid >> 6, lane = tid & 63;
    const int l = blockIdx.x * 1024 + tid;

    if (tid < DD) {
        float c = 0.f;
        #pragma unroll
        for (int p = 0; p < 16; ++p) c += comp_part[p * DD + tid];
        shc[tid] = c * (1.f / N_ATOMS);
    }
    __syncthreads();

    float h[DD];
    #pragma unroll
    for (int d = 0; d < DD; ++d) {
        float v = ba[d];
        #pragma unroll
        for (int k = 0; k < DD; ++k) v += Wa[d * DD + k] * shc[k];
        h[d] = fmaxf(v, 0.f);
    }

    float row[DD];
    #pragma unroll
    for (int d = 0; d < DD; ++d) row[d] = xs_p[(size_t)l * DD + d];

    float hp[DD], dotv = 0.f;
    #pragma unroll
    for (int d = 0; d < DD; ++d) {
        float v = ba[d];
        #pragma unroll
        for (int k = 0; k < DD; ++k) v += Wa[d * DD + k] * row[k];
        hp[d] = fmaxf(v, 0.f);
        dotv += h[d] * hp[d];
    }
    const float wgt = tanhf(dotv);

    float y[DD];
    #pragma unroll
    for (int d = 0; d < DD; ++d) y[d] = wgt * hp[d];
    #pragma unroll
    for (int m = 32; m >= 1; m >>= 1) {
        #pragma unroll
        for (int d = 0; d < DD; ++d) y[d] += __shfl_xor(y[d], m, 64);
    }
    if (lane == 0) {
        #pragma unroll
        for (int d = 0; d < DD; ++d) s[wave][d] = y[d];
    }
    __syncthreads();
    if (tid < DD) {
        float v = 0.f;
        #pragma unroll
        for (int wv = 0; wv < 16; ++wv) v += s[wv][tid];
        att_part[blockIdx.x * DD + tid] = v;
    }
}

// ---------------------------------------------------------------------------
// K4: final MLP (comp + protein derived in-block)
// ---------------------------------------------------------------------------
__global__ __launch_bounds__(64) void final_mlp(
    const float* __restrict__ comp_part, const float* __restrict__ att_part,
    const float* __restrict__ Wo, const float* __restrict__ bo,
    const float* __restrict__ Wi, const float* __restrict__ bi,
    float* __restrict__ out)
{
    const int t = threadIdx.x;
    float a[DD];
    #pragma unroll
    for (int d = 0; d < DD; ++d) a[d] = att_part[t * DD + d];
    #pragma unroll
    for (int m = 32; m >= 1; m >>= 1) {
        #pragma unroll
        for (int d = 0; d < DD; ++d) a[d] += __shfl_xor(a[d], m, 64);
    }
    __shared__ float cat[20];
    if (t < DD) {
        float c = 0.f;
        #pragma unroll
        for (int p = 0; p < 16; ++p) c += comp_part[p * DD + t];
        cat[t] = c * (1.f / N_ATOMS);
    }
    if (t == 0) {
        #pragma unroll
        for (int d = 0; d < DD; ++d) cat[DD + d] = a[d] * (1.f / L_WORDS);
    }
    __syncthreads();
    for (int j = 0; j < 3; ++j) {
        float v = 0.f;
        if (t < 20) {
            v = bo[j * 20 + t];
            for (int k = 0; k < 20; ++k) v += Wo[j * 400 + t * 20 + k] * cat[k];
        }
        __syncthreads();
        if (t < 20) cat[t] = fmaxf(v, 0.f);
        __syncthreads();
    }
    if (t < 2) {
        float v = bi[t];
        for (int k = 0; k < 20; ++k) v += Wi[t * 20 + k] * cat[k];
        out[t] = v;
    }
}

// ---------------------------------------------------------------------------
extern "C" void kernel_launch(void* const* d_in, const int* in_sizes, int n_in,
                              void* d_out, int out_size, void* d_ws, size_t ws_size,
                              hipStream_t stream)
{
    const int*   fp     = (const int*)d_in[0];
    const float* A      = (const float*)d_in[1];
    const int*   words  = (const int*)d_in[2];
    const float* emb_fp = (const float*)d_in[3];
    const float* emb_w  = (const float*)d_in[4];
    const float* Wg     = (const float*)d_in[5];   // [3][10][10]
    const float* bg     = (const float*)d_in[6];   // [3][10]
    const float* Wc     = (const float*)d_in[7];   // [3][529]
    const float* bc     = (const float*)d_in[8];   // [3]
    const float* Wa     = (const float*)d_in[9];   // [10][10]
    const float* ba     = (const float*)d_in[10];  // [10]
    const float* Wo     = (const float*)d_in[11];  // [3][20][20]
    const float* bo     = (const float*)d_in[12];  // [3][20]
    const float* Wi     = (const float*)d_in[13];  // [2][20]
    const float* bi     = (const float*)d_in[14];  // [2]
    float* out = (float*)d_out;
    float* ws  = (float*)d_ws;

    float* ta    = ws;                       // 655360
    float* tb    = ws + 655360;              // 655360
    float* part0 = ws + 1310720;             // 163840 ([4096][4][10])
    float* part1 = ws + 1474560;             // 163840
    float* part2 = ws + 1638400;             // 163840
    float* comp_part = ws + 1802240;         // 160
    float* att_part  = ws + 1802496;         // 640

    const int fused_grid = CONV_BLOCKS + GNN_BLOCKS;   // 768 = 3 blocks/CU

    // All cross-layer ordering via kernel boundaries (no atomics/fences).
    fused_layer<<<fused_grid, 256, 0, stream>>>(
        A, fp, emb_fp, nullptr, nullptr, part0, Wg, bg,
        nullptr, words, emb_w, Wc, bc, ta);

    fused_layer<<<fused_grid, 256, 0, stream>>>(
        A, fp, emb_fp, part0, nullptr, part1, Wg + 100, bg + 10,
        ta, nullptr, nullptr, Wc + 529, bc + 1, tb);

    fused_layer<<<fused_grid, 256, 0, stream>>>(
        A, fp, emb_fp, part0, part1, part2, Wg + 200, bg + 20,
        tb, nullptr, nullptr, Wc + 1058, bc + 2, ta);

    comp_reduce<<<16, 256, 0, stream>>>(fp, emb_fp, part0, part1, part2, comp_part);

    attention_pool<<<L_WORDS / 1024, 1024, 0, stream>>>(
        ta, comp_part, Wa, ba, att_part);

    final_mlp<<<1, 64, 0, stream>>>(comp_part, att_part, Wo, bo, Wi, bi, out);
}